// Round 1
// baseline (11.419 us; speedup 1.0000x reference)
//
#include <hip/hip_runtime.h>
#include <math.h>

// SSA loss:
//   xn = x / max(||x||_2, 1e-12) per row (dim=1)
//   corr[m] = per-sample outer products xn xn^T  (never materialized here)
//   dist(m,n) = sqrt(1e-12 + sum_b(||a_b||^4 + ||c_b||^4 - 2 (a_b . c_b)^2))
//   ssa[m] = sum_n focal(loss_m - loss_n) * dist(m,n),
//   focal(d) = log(0.5*d + 1) if d > 1e-12 else 0
//
// B=128, D=512, fp32 in/out. Work is O(B*D): launch-latency-bound.

#define SSA_BETA      0.5f
#define SSA_THRESHOLD 1e-12f
#define SSA_NORM_EPS  1e-12f
#define SSA_SQRT_EPS  1e-12f

static constexpr int SSA_B = 128;
static constexpr int SSA_D = 512;

// Kernel 1: one block (1 wave of 64 lanes) per row b.
// Each lane loads 2 float4 per modality (coalesced: lane i -> float4 index i
// and i+64). Accumulate 6 partial sums, butterfly-reduce across the wave,
// lane 0 writes the 3 pair contributions:
//   ws[0*128 + b] : pair (audio, video)
//   ws[1*128 + b] : pair (audio, text)
//   ws[2*128 + b] : pair (video, text)
__global__ __launch_bounds__(64) void ssa_rows_kernel(
    const float* __restrict__ xa, const float* __restrict__ xv,
    const float* __restrict__ xt, float* __restrict__ ws) {
  const int b = blockIdx.x;
  const int lane = threadIdx.x;

  const float4* pa = reinterpret_cast<const float4*>(xa + b * SSA_D);
  const float4* pv = reinterpret_cast<const float4*>(xv + b * SSA_D);
  const float4* pt = reinterpret_cast<const float4*>(xt + b * SSA_D);

  float sa = 0.f, sv = 0.f, st = 0.f;     // squared norms
  float dav = 0.f, dat = 0.f, dvt = 0.f;  // dot products

#pragma unroll
  for (int k = 0; k < 2; ++k) {
    const int idx = lane + 64 * k;  // float4 index within the row (0..127)
    const float4 a = pa[idx];
    const float4 v = pv[idx];
    const float4 t = pt[idx];
    sa  += a.x * a.x + a.y * a.y + a.z * a.z + a.w * a.w;
    sv  += v.x * v.x + v.y * v.y + v.z * v.z + v.w * v.w;
    st  += t.x * t.x + t.y * t.y + t.z * t.z + t.w * t.w;
    dav += a.x * v.x + a.y * v.y + a.z * v.z + a.w * v.w;
    dat += a.x * t.x + a.y * t.y + a.z * t.z + a.w * t.w;
    dvt += v.x * t.x + v.y * t.y + v.z * t.z + v.w * t.w;
  }

  // Butterfly reduction across the 64-lane wave.
#pragma unroll
  for (int off = 32; off > 0; off >>= 1) {
    sa  += __shfl_xor(sa, off);
    sv  += __shfl_xor(sv, off);
    st  += __shfl_xor(st, off);
    dav += __shfl_xor(dav, off);
    dat += __shfl_xor(dat, off);
    dvt += __shfl_xor(dvt, off);
  }

  if (lane == 0) {
    const float na = fmaxf(sqrtf(sa), SSA_NORM_EPS);
    const float nv = fmaxf(sqrtf(sv), SSA_NORM_EPS);
    const float nt = fmaxf(sqrtf(st), SSA_NORM_EPS);
    // squared norms of the *normalized* rows (== 1 up to fp rounding)
    const float na2 = sa / (na * na);
    const float nv2 = sv / (nv * nv);
    const float nt2 = st / (nt * nt);
    // normalized dot products
    const float cav = dav / (na * nv);
    const float cat_ = dat / (na * nt);
    const float cvt_ = dvt / (nv * nt);
    ws[0 * SSA_B + b] = na2 * na2 + nv2 * nv2 - 2.f * cav * cav;
    ws[1 * SSA_B + b] = na2 * na2 + nt2 * nt2 - 2.f * cat_ * cat_;
    ws[2 * SSA_B + b] = nv2 * nv2 + nt2 * nt2 - 2.f * cvt_ * cvt_;
  }
}

// Kernel 2: single block, 128 threads (2 waves). Thread b reads the 3 pair
// contributions for row b, block-reduce, thread 0 applies focal weights.
__global__ __launch_bounds__(128) void ssa_final_kernel(
    const float* __restrict__ ws, const float* __restrict__ la,
    const float* __restrict__ lv, const float* __restrict__ lt,
    float* __restrict__ out) {
  const int tid = threadIdx.x;
  float s0 = ws[0 * SSA_B + tid];
  float s1 = ws[1 * SSA_B + tid];
  float s2 = ws[2 * SSA_B + tid];

#pragma unroll
  for (int off = 32; off > 0; off >>= 1) {
    s0 += __shfl_xor(s0, off);
    s1 += __shfl_xor(s1, off);
    s2 += __shfl_xor(s2, off);
  }

  __shared__ float sm[3][2];
  const int wave = tid >> 6;
  if ((tid & 63) == 0) {
    sm[0][wave] = s0;
    sm[1][wave] = s1;
    sm[2][wave] = s2;
  }
  __syncthreads();

  if (tid == 0) {
    const float S01 = sm[0][0] + sm[0][1];  // (audio, video)
    const float S02 = sm[1][0] + sm[1][1];  // (audio, text)
    const float S12 = sm[2][0] + sm[2][1];  // (video, text)

    const float dist01 = sqrtf(SSA_SQRT_EPS + S01);
    const float dist02 = sqrtf(SSA_SQRT_EPS + S02);
    const float dist12 = sqrtf(SSA_SQRT_EPS + S12);

    const float loss[3] = {la[0], lv[0], lt[0]};
    // symmetric pair distance lookup; diagonal unused (focal(0) == 0)
    const float dist[3][3] = {{0.f, dist01, dist02},
                              {dist01, 0.f, dist12},
                              {dist02, dist12, 0.f}};
#pragma unroll
    for (int m = 0; m < 3; ++m) {
      float acc = 0.f;
#pragma unroll
      for (int n = 0; n < 3; ++n) {
        if (n == m) continue;
        const float d = loss[m] - loss[n];
        const float focal = (d > SSA_THRESHOLD) ? logf(SSA_BETA * d + 1.0f) : 0.f;
        acc += focal * dist[m][n];
      }
      out[m] = acc;
    }
  }
}

extern "C" void kernel_launch(void* const* d_in, const int* in_sizes, int n_in,
                              void* d_out, int out_size, void* d_ws, size_t ws_size,
                              hipStream_t stream) {
  const float* xa = (const float*)d_in[0];
  const float* xv = (const float*)d_in[1];
  const float* xt = (const float*)d_in[2];
  const float* la = (const float*)d_in[3];
  const float* lv = (const float*)d_in[4];
  const float* lt = (const float*)d_in[5];
  float* out = (float*)d_out;
  float* ws = (float*)d_ws;  // needs 3*128 floats = 1536 B

  ssa_rows_kernel<<<SSA_B, 64, 0, stream>>>(xa, xv, xt, ws);
  ssa_final_kernel<<<1, 128, 0, stream>>>(ws, la, lv, lt, out);
}